// Round 6
// baseline (3037.696 us; speedup 1.0000x reference)
//
#include <hip/hip_runtime.h>
#include <hip/hip_bf16.h>
#include <math.h>

typedef __bf16 bf16x8 __attribute__((ext_vector_type(8)));
typedef float floatx4 __attribute__((ext_vector_type(4)));

#define T_LEN 128

// ws layout: bf16 fragment-packed weights, gates KI-MAJOR:
//   gate frag addr = WP_OFF + ki*65536 + ct*1024 + lane*16
// Gate K order: [ h(0..255) | z(256..287) | a(288..295) | pad(296..319) ]
//   ki0..7 = h, ki8 = z, ki9 = a+pad
#define WP_OFF   0
#define WP_SZ    (64*10*64*16)     // 655360
#define W1P_OFF  (WP_OFF + WP_SZ)
#define W1P_SZ   (8*8*64*16)       // 65536
#define W2P_OFF  (W1P_OFF + W1P_SZ)
#define W2P_SZ   (8*4*64*16)       // 32768
#define WZP_OFF  (W2P_OFF + W2P_SZ)
#define WZP_SZ   (4*4*64*16)       // 16384
#define WS_NEEDED ((size_t)(WZP_OFF + WZP_SZ))   // 770048 B

// ---- fast transcendentals ------------------------------------------------
#if __has_builtin(__builtin_amdgcn_exp2f)
#define EXP2F(x) __builtin_amdgcn_exp2f(x)
#else
#define EXP2F(x) exp2f(x)
#endif
#if __has_builtin(__builtin_amdgcn_logf)
#define LOG2F(x) __builtin_amdgcn_logf(x)
#else
#define LOG2F(x) log2f(x)
#endif
#if __has_builtin(__builtin_amdgcn_rcpf)
#define RCPF(x) __builtin_amdgcn_rcpf(x)
#else
#define RCPF(x) (1.0f/(x))
#endif

__device__ __forceinline__ float fsigmoid(float x) {
    return RCPF(1.0f + EXP2F(-1.4426950408889634f * x));
}
__device__ __forceinline__ float ftanh(float x) {
    return 1.0f - 2.0f * RCPF(1.0f + EXP2F(2.8853900817779268f * x));
}

// raw barrier: LDS writes visible, VMEM loads STAY IN FLIGHT (no vmcnt drain)
#define BAR() do {                                                  \
    asm volatile("s_waitcnt lgkmcnt(0)" ::: "memory");              \
    __builtin_amdgcn_sched_barrier(0);                              \
    __builtin_amdgcn_s_barrier();                                   \
    __builtin_amdgcn_sched_barrier(0);                              \
} while (0)

// ---------------- prep: f32 weights -> bf16 B-fragment-linear in ws -------
__global__ void prep_kernel(const float* __restrict__ Wih, const float* __restrict__ Whh,
                            const float* __restrict__ W1,  const float* __restrict__ W2,
                            const float* __restrict__ Wz,  unsigned char* __restrict__ ws)
{
    int id = blockIdx.x * blockDim.x + threadIdx.x;
    __bf16* Wp  = (__bf16*)(ws + WP_OFF);
    __bf16* W1p = (__bf16*)(ws + W1P_OFF);
    __bf16* W2p = (__bf16*)(ws + W2P_OFF);
    __bf16* Wzp = (__bf16*)(ws + WZP_OFF);
    if (id < 40960) {                       // gates: 64 ct x 10 ki x 64 lanes
        int ct = id / 640, rem = id % 640;
        int ki = rem / 64, lane = rem % 64;
        int row = ct * 16 + (lane & 15);                 // gate-output col
        int kb  = ki * 32 + (lane >> 4) * 8;
        for (int j = 0; j < 8; ++j) {
            int k = kb + j;
            float v;
            if (k < 256)      v = Whh[row * 256 + k];            // h block
            else if (k < 288) v = Wih[row * 40 + 8 + (k - 256)]; // z block
            else if (k < 296) v = Wih[row * 40 + (k - 288)];     // a block
            else              v = 0.0f;                          // pad
            Wp[((size_t)(ki * 64 + ct) * 64 + lane) * 8 + j] = (__bf16)v;
        }
    } else if (id < 45056) {                // W1: 8 ct x 8 ki (ct-major)
        int id2 = id - 40960;
        int rem = id2 % 512, lane = rem % 64;
        int row = (id2 / 512) * 16 + (lane & 15);
        int kb  = (rem / 64) * 32 + (lane >> 4) * 8;
        for (int j = 0; j < 8; ++j) W1p[(size_t)id2 * 8 + j] = (__bf16)W1[row * 256 + kb + j];
    } else if (id < 47104) {                // W2: 8 ct x 4 ki
        int id3 = id - 45056;
        int rem = id3 % 256, lane = rem % 64;
        int row = (id3 / 256) * 16 + (lane & 15);
        int kb  = (rem / 64) * 32 + (lane >> 4) * 8;
        for (int j = 0; j < 8; ++j) W2p[(size_t)id3 * 8 + j] = (__bf16)W2[row * 128 + kb + j];
    } else if (id < 48128) {                // Wz: 4 ct x 4 ki
        int id4 = id - 47104;
        int rem = id4 % 256, lane = rem % 64;
        int row = (id4 / 256) * 16 + (lane & 15);
        int kb  = (rem / 64) * 32 + (lane >> 4) * 8;
        for (int j = 0; j < 8; ++j) Wzp[(size_t)id4 * 8 + j] = (__bf16)Wz[row * 128 + kb + j];
    }
}

// ---------------- fast path: 64 blocks x 1024 threads (16 waves) ----------
// R6: gates || MLP wave specialization, 2 raw barriers/step, no vmcnt drains.
//  Waves 0-7  (gate): gates-h+a(t) [9 slabs, reg A/B stream] ; after B_z:
//                     gates-z(t) [1 slab] + LSTM cell -> h(t+1).
//  Waves 8-15 (MLP):  u1->u2->zz->softplus->z(t-1) from LDS-resident MLP
//                     weights, concurrent with gates-h. Internal handoffs
//                     via monotonic LDS counters (back-pressured by B_z/B_h).
// xh cols: [ h(0..255) | z(256..287) | a(288..295) | pad(..319) ]
__global__ __launch_bounds__(1024) void seq_mfma(
    const float* __restrict__ A,   const float* __restrict__ eps,
    const float* __restrict__ z0,  const float* __restrict__ h0,
    const float* __restrict__ c0,
    const float* __restrict__ bih, const float* __restrict__ bhh,
    const float* __restrict__ b1,  const float* __restrict__ b2,
    const float* __restrict__ bz,
    const unsigned char* __restrict__ ws, float* __restrict__ out)
{
    const int tid  = threadIdx.x;
    const int wave = tid >> 6;
    const int lane = tid & 63;
    const int lrow = lane & 15;
    const int quad = lane >> 4;
    const int n0   = blockIdx.x * 16;

    __shared__ __align__(16) __bf16 wmlp[(W1P_SZ + W2P_SZ + WZP_SZ) / 2];  // 112 KB
    __shared__ __align__(16) __bf16 xh[2][16][328];
    __shared__ __align__(16) __bf16 u1s[16][136];
    __shared__ __align__(16) __bf16 u2s[16][136];
    __shared__ int c1s, c2s;

    {   // one-time: MLP weights global -> LDS (7168 x 16B)
        const float4* src = (const float4*)(ws + W1P_OFF);
        float4* dst = (float4*)wmlp;
        for (int i = tid; i < 7168; i += 1024) dst[i] = src[i];
    }
    // init xh: h0 | z0 | (a: buffer0 staged below) | pad 0
    for (int idx = tid; idx < 2 * 16 * 320; idx += 1024) {
        int b = idx / (16 * 320);
        int rem = idx % (16 * 320);
        int r = rem / 320, col = rem % 320;
        if (b == 0 && col >= 288 && col < 296) continue;   // a(0) staged below
        float v;
        if (col < 256)      v = h0[col];
        else if (col < 288) v = z0[col - 256];
        else                v = 0.0f;
        xh[b][r][col] = (__bf16)v;
    }
    if (tid < 128)   // a(t=0)
        xh[0][tid >> 3][288 + (tid & 7)] =
            (__bf16)A[((size_t)(n0 + (tid >> 3)) * T_LEN + 0) * 8 + (tid & 7)];
    if (tid == 0) { c1s = 0; c2s = 0; }
    __syncthreads();

    if (wave < 8) {
        // ======================= GATE WAVES =======================
        const int w = wave;
        const char* wsb = (const char*)ws;

        float gb[4][2];
        #pragma unroll
        for (int g = 0; g < 4; ++g)
            #pragma unroll
            for (int j = 0; j < 2; ++j) {
                int unit = 32 * w + 16 * j + lrow;
                gb[g][j] = bih[g * 256 + unit] + bhh[g * 256 + unit];
            }
        float cst[2][4];
        #pragma unroll
        for (int j = 0; j < 2; ++j) {
            float cv = c0[32 * w + 16 * j + lrow];
            #pragma unroll
            for (int r = 0; r < 4; ++r) cst[j][r] = cv;
        }

        #define GLOAD(BUF, KI) do {                                                   \
            _Pragma("unroll")                                                         \
            for (int g_ = 0; g_ < 4; ++g_)                                            \
                _Pragma("unroll")                                                     \
                for (int j_ = 0; j_ < 2; ++j_)                                        \
                    BUF[g_][j_] = *(const bf16x8*)(wsb + WP_OFF + (KI) * 65536 +      \
                        ((size_t)(g_ * 16 + 2 * w + j_) * 1024 + (size_t)lane * 16)); \
        } while (0)
        #define GMFMA(KI, BUF) do {                                                   \
            bf16x8 af_ = *(const bf16x8*)&xh[cb][lrow][(KI) * 32 + quad * 8];         \
            _Pragma("unroll")                                                         \
            for (int g_ = 0; g_ < 4; ++g_)                                            \
                _Pragma("unroll")                                                     \
                for (int j_ = 0; j_ < 2; ++j_)                                        \
                    acc[g_][j_] = __builtin_amdgcn_mfma_f32_16x16x32_bf16(            \
                        af_, BUF[g_][j_], acc[g_][j_], 0, 0, 0);                      \
        } while (0)

        bf16x8 bwA[4][2], bwB[4][2];
        GLOAD(bwA, 0);
        GLOAD(bwB, 1);

        for (int t = 0; t < T_LEN; ++t) {
            const int cb = t & 1;
            const int nb = cb ^ 1;

            floatx4 acc[4][2];
            #pragma unroll
            for (int g = 0; g < 4; ++g)
                #pragma unroll
                for (int j = 0; j < 2; ++j)
                    acc[g][j] = (floatx4){gb[g][j], gb[g][j], gb[g][j], gb[g][j]};

            // interval 1: h-slabs 0..7 + a-slab 9 ; rolling A/B prefetch
            GMFMA(0, bwA);  GLOAD(bwA, 2);
            GMFMA(1, bwB);  GLOAD(bwB, 3);
            GMFMA(2, bwA);  GLOAD(bwA, 4);
            GMFMA(3, bwB);  GLOAD(bwB, 5);
            GMFMA(4, bwA);  GLOAD(bwA, 6);
            GMFMA(5, bwB);  GLOAD(bwB, 7);
            GMFMA(6, bwA);  GLOAD(bwA, 9);
            GMFMA(7, bwB);  GLOAD(bwB, 8);
            GMFMA(9, bwA);  GLOAD(bwA, 0);   // next-t slab 0 (in flight across BAR)

            BAR();   // B_z: z(t-1) now staged in xh[cb] by MLP waves

            // interval 2: z-slab + cell
            GMFMA(8, bwB);  GLOAD(bwB, 1);   // next-t slab 1
            #pragma unroll
            for (int j = 0; j < 2; ++j)
                #pragma unroll
                for (int r = 0; r < 4; ++r) {
                    float iv = fsigmoid(acc[0][j][r]);
                    float fv = fsigmoid(acc[1][j][r]);
                    float gv = ftanh(acc[2][j][r]);
                    float ov = fsigmoid(acc[3][j][r]);
                    float cn = fv * cst[j][r] + iv * gv;
                    cst[j][r] = cn;
                    xh[nb][quad * 4 + r][32 * w + 16 * j + lrow] = (__bf16)(ov * ftanh(cn));
                }

            BAR();   // B_h: h(t+1) + a(t+1) staged in xh[nb]
        }
        #undef GLOAD
        #undef GMFMA
        return;   // MLP waves finish the epilogue alone (no barriers there)
    }

    // ======================= MLP WAVES =======================
    const int w2 = wave - 8;
    const __bf16* w1l = wmlp;                  // ct*4096 + ki*512 + lane*8
    const __bf16* w2l = wmlp + 32768;          // ct*2048 + ki*512 + lane*8
    const __bf16* wzl = wmlp + 32768 + 16384;  // ct*2048 + ki*512 + lane*8

    float u1b = b1[w2 * 16 + lrow];
    float u2b = b2[w2 * 16 + lrow];
    float bzl = bz[(w2 & 1) * 16 + lrow];
    float bzr = bz[32 + (w2 & 1) * 16 + lrow];
    float epsr[4] = {0, 0, 0, 0};
    float zvp[4]  = {0, 0, 0, 0};

    // MLP body for step index TT (computes z(TT-1) from h(TT) in xh[CBUF]).
    // WRZ: 1 -> also write z into xh[CBUF] (feedback); 0 -> epilogue (out only)
    #define MLP_BODY(CBUF, TT, WRZ) do {                                              \
        floatx4 a1 = (floatx4){u1b, u1b, u1b, u1b};                                   \
        _Pragma("unroll")                                                             \
        for (int ki = 0; ki < 8; ++ki) {                                              \
            bf16x8 af = *(const bf16x8*)&xh[CBUF][lrow][ki * 32 + quad * 8];          \
            bf16x8 bb = *(const bf16x8*)&w1l[w2 * 4096 + ki * 512 + lane * 8];        \
            a1 = __builtin_amdgcn_mfma_f32_16x16x32_bf16(af, bb, a1, 0, 0, 0);        \
        }                                                                             \
        _Pragma("unroll")                                                             \
        for (int r = 0; r < 4; ++r)                                                   \
            u1s[quad * 4 + r][w2 * 16 + lrow] = (__bf16)fmaxf(a1[r], 0.0f);           \
        asm volatile("s_waitcnt lgkmcnt(0)" ::: "memory");                            \
        __builtin_amdgcn_sched_barrier(0);                                            \
        if (lane == 0) atomicAdd(&c1s, 1);                                            \
        while (*(volatile int*)&c1s < 8 * (TT)) __builtin_amdgcn_s_sleep(1);          \
        __builtin_amdgcn_sched_barrier(0);                                            \
        floatx4 a2 = (floatx4){u2b, u2b, u2b, u2b};                                   \
        _Pragma("unroll")                                                             \
        for (int ki = 0; ki < 4; ++ki) {                                              \
            bf16x8 af = *(const bf16x8*)&u1s[lrow][ki * 32 + quad * 8];               \
            bf16x8 bb = *(const bf16x8*)&w2l[w2 * 2048 + ki * 512 + lane * 8];        \
            a2 = __builtin_amdgcn_mfma_f32_16x16x32_bf16(af, bb, a2, 0, 0, 0);        \
        }                                                                             \
        _Pragma("unroll")                                                             \
        for (int r = 0; r < 4; ++r)                                                   \
            u2s[quad * 4 + r][w2 * 16 + lrow] = (__bf16)fmaxf(a2[r], 0.0f);           \
        asm volatile("s_waitcnt lgkmcnt(0)" ::: "memory");                            \
        __builtin_amdgcn_sched_barrier(0);                                            \
        if (lane == 0) atomicAdd(&c2s, 1);                                            \
        if (w2 < 2) {                                                                 \
            while (*(volatile int*)&c2s < 8 * (TT)) __builtin_amdgcn_s_sleep(1);      \
            __builtin_amdgcn_sched_barrier(0);                                        \
            floatx4 aL = (floatx4){bzl, bzl, bzl, bzl};                               \
            floatx4 aR = (floatx4){bzr, bzr, bzr, bzr};                               \
            _Pragma("unroll")                                                         \
            for (int ki = 0; ki < 4; ++ki) {                                          \
                bf16x8 af = *(const bf16x8*)&u2s[lrow][ki * 32 + quad * 8];           \
                bf16x8 bl = *(const bf16x8*)&wzl[(w2)     * 2048 + ki * 512 + lane * 8]; \
                bf16x8 br = *(const bf16x8*)&wzl[(w2 + 2) * 2048 + ki * 512 + lane * 8]; \
                aL = __builtin_amdgcn_mfma_f32_16x16x32_bf16(af, bl, aL, 0, 0, 0);    \
                aR = __builtin_amdgcn_mfma_f32_16x16x32_bf16(af, br, aR, 0, 0, 0);    \
            }                                                                         \
            _Pragma("unroll")                                                         \
            for (int r = 0; r < 4; ++r) {                                             \
                float raw = aR[r];                                                    \
                float sp  = (raw > 20.0f)                                             \
                          ? raw                                                       \
                          : 0.6931471805599453f *                                     \
                            LOG2F(1.0f + EXP2F(1.4426950408889634f * raw));           \
                float zv  = aL[r] + sp * epsr[r];                                     \
                zvp[r] = zv;                                                          \
                if (WRZ)                                                              \
                    xh[CBUF][quad * 4 + r][256 + w2 * 16 + lrow] = (__bf16)zv;        \
            }                                                                         \
        }                                                                             \
    } while (0)

    for (int t = 0; t < T_LEN; ++t) {
        const int cb = t & 1;
        const int nb = cb ^ 1;

        // interval 1: MLP(t-1) -> z(t-1), concurrent with gates-h(t)
        if (t > 0)
            MLP_BODY(cb, t, 1);

        BAR();   // B_z

        // interval 2 (light): deferred out-store, eps(t) prefetch, a(t+1) stage
        if (w2 < 2) {
            if (t > 0) {
                #pragma unroll
                for (int r = 0; r < 4; ++r)
                    out[((size_t)(n0 + quad * 4 + r) * T_LEN + (t - 1)) * 32 + w2 * 16 + lrow]
                        = zvp[r];
            }
            #pragma unroll
            for (int r = 0; r < 4; ++r)
                epsr[r] = eps[((size_t)(n0 + quad * 4 + r) * T_LEN + t) * 32 + w2 * 16 + lrow];
        } else if (w2 == 2 || w2 == 3) {
            if (t + 1 < T_LEN) {
                int atid = (w2 - 2) * 64 + lane;
                float av = A[((size_t)(n0 + (atid >> 3)) * T_LEN + (t + 1)) * 8 + (atid & 7)];
                xh[nb][atid >> 3][288 + (atid & 7)] = (__bf16)av;
            }
        }

        BAR();   // B_h
    }

    // epilogue: z(127) from h(128) (in xh[0]); out-store only, no barriers
    MLP_BODY(0, T_LEN, 0);
    if (w2 < 2) {
        #pragma unroll
        for (int r = 0; r < 4; ++r)
            out[((size_t)(n0 + quad * 4 + r) * T_LEN + (T_LEN - 1)) * 32 + w2 * 16 + lrow]
                = zvp[r];
    }
    #undef MLP_BODY
}

// ---------------- fallback: proven R4 VALU kernel (f32 hard-coded) --------
struct SM {
    float zx[4][40]; float h[4][256]; float u1[4][128]; float u2[4][128]; float zz[4][64];
};

__global__ __launch_bounds__(256) void seq_valu(
    const float* __restrict__ A, const float* __restrict__ eps,
    const float* __restrict__ z0, const float* __restrict__ h0, const float* __restrict__ c0,
    const float* __restrict__ Wih, const float* __restrict__ Whh,
    const float* __restrict__ bih, const float* __restrict__ bhh,
    const float* __restrict__ W1, const float* __restrict__ b1,
    const float* __restrict__ W2, const float* __restrict__ b2,
    const float* __restrict__ Wz, const float* __restrict__ bz, float* __restrict__ out)
{
    __shared__ SM sm;
    const int tid = threadIdx.x;
    const int n0  = blockIdx.x * 4;
    if (tid < 128) { int rr = tid >> 5, cc = tid & 31; sm.zx[rr][8 + cc] = z0[cc]; }
    for (int i = tid; i < 4 * 256; i += 256) sm.h[i >> 8][i & 255] = h0[i & 255];
    float c[4];
    #pragma unroll
    for (int rr = 0; rr < 4; ++rr) c[rr] = c0[tid];
    float gbias[4];
    #pragma unroll
    for (int g = 0; g < 4; ++g) gbias[g] = bih[g * 256 + tid] + bhh[g * 256 + tid];

    for (int t = 0; t < T_LEN; ++t) {
        if (tid < 32) { int rr = tid >> 3, cc = tid & 7;
            sm.zx[rr][cc] = A[((size_t)(n0 + rr) * T_LEN + t) * 8 + cc]; }
        __syncthreads();
        float acc[4][4];
        #pragma unroll
        for (int g = 0; g < 4; ++g)
            #pragma unroll
            for (int rr = 0; rr < 4; ++rr) acc[g][rr] = gbias[g];
        for (int k = 0; k < 40; ++k) {
            float xv[4];
            #pragma unroll
            for (int rr = 0; rr < 4; ++rr) xv[rr] = sm.zx[rr][k];
            #pragma unroll
            for (int g = 0; g < 4; ++g) {
                float w = Wih[(size_t)(g * 256 + tid) * 40 + k];
                #pragma unroll
                for (int rr = 0; rr < 4; ++rr) acc[g][rr] += w * xv[rr];
            }
        }
        for (int k = 0; k < 256; ++k) {
            float hv[4];
            #pragma unroll
            for (int rr = 0; rr < 4; ++rr) hv[rr] = sm.h[rr][k];
            #pragma unroll
            for (int g = 0; g < 4; ++g) {
                float w = Whh[(size_t)(g * 256 + tid) * 256 + k];
                #pragma unroll
                for (int rr = 0; rr < 4; ++rr) acc[g][rr] += w * hv[rr];
            }
        }
        __syncthreads();
        #pragma unroll
        for (int rr = 0; rr < 4; ++rr) {
            float iv = 1.0f / (1.0f + expf(-acc[0][rr]));
            float fv = 1.0f / (1.0f + expf(-acc[1][rr]));
            float gv = tanhf(acc[2][rr]);
            float ov = 1.0f / (1.0f + expf(-acc[3][rr]));
            float cn = fv * c[rr] + iv * gv;
            c[rr] = cn;
            sm.h[rr][tid] = ov * tanhf(cn);
        }
        __syncthreads();
        { int col = tid & 127, rb = (tid >> 7) * 2;
          float a0 = b1[col], a1 = a0;
          for (int k = 0; k < 256; ++k) { float w = W1[(size_t)col * 256 + k];
              a0 += w * sm.h[rb][k]; a1 += w * sm.h[rb + 1][k]; }
          sm.u1[rb][col] = fmaxf(a0, 0.0f); sm.u1[rb + 1][col] = fmaxf(a1, 0.0f); }
        __syncthreads();
        { int col = tid & 127, rb = (tid >> 7) * 2;
          float a0 = b2[col], a1 = a0;
          for (int k = 0; k < 128; ++k) { float w = W2[(size_t)col * 128 + k];
              a0 += w * sm.u1[rb][k]; a1 += w * sm.u1[rb + 1][k]; }
          sm.u2[rb][col] = fmaxf(a0, 0.0f); sm.u2[rb + 1][col] = fmaxf(a1, 0.0f); }
        __syncthreads();
        { int rr = tid >> 6, col = tid & 63;
          float a0 = bz[col];
          for (int k = 0; k < 128; ++k) a0 += Wz[(size_t)col * 128 + k] * sm.u2[rr][k];
          sm.zz[rr][col] = a0; }
        __syncthreads();
        if (tid < 128) {
            int rr = tid >> 5, cc = tid & 31;
            float loc = sm.zz[rr][cc], raw = sm.zz[rr][cc + 32];
            float sp  = (raw > 20.0f) ? raw : log1pf(expf(raw));
            float ev  = eps[((size_t)(n0 + rr) * T_LEN + t) * 32 + cc];
            float zv  = loc + sp * ev;
            sm.zx[rr][8 + cc] = zv;
            out[((size_t)(n0 + rr) * T_LEN + t) * 32 + cc] = zv;
        }
        __syncthreads();
    }
}

extern "C" void kernel_launch(void* const* d_in, const int* in_sizes, int n_in,
                              void* d_out, int out_size, void* d_ws, size_t ws_size,
                              hipStream_t stream)
{
    const float* A   = (const float*)d_in[0];
    const float* eps = (const float*)d_in[1];
    const float* z0  = (const float*)d_in[2];
    const float* h0  = (const float*)d_in[3];
    const float* c0  = (const float*)d_in[4];
    const float* Wih = (const float*)d_in[5];
    const float* Whh = (const float*)d_in[6];
    const float* bih = (const float*)d_in[7];
    const float* bhh = (const float*)d_in[8];
    const float* W1  = (const float*)d_in[9];
    const float* b1  = (const float*)d_in[10];
    const float* W2  = (const float*)d_in[11];
    const float* b2  = (const float*)d_in[12];
    const float* Wz  = (const float*)d_in[13];
    const float* bz  = (const float*)d_in[14];
    float* out = (float*)d_out;

    if (ws_size >= WS_NEEDED) {
        prep_kernel<<<188, 256, 0, stream>>>(Wih, Whh, W1, W2, Wz, (unsigned char*)d_ws);
        seq_mfma<<<64, 1024, 0, stream>>>(A, eps, z0, h0, c0,
                                          bih, bhh, b1, b2, bz,
                                          (const unsigned char*)d_ws, out);
    } else {
        seq_valu<<<256, 256, 0, stream>>>(A, eps, z0, h0, c0, Wih, Whh, bih, bhh,
                                          W1, b1, W2, b2, Wz, bz, out);
    }
}

// Round 7
// 2160.111 us; speedup vs baseline: 1.4063x; 1.4063x over previous
//
#include <hip/hip_runtime.h>
#include <hip/hip_bf16.h>
#include <math.h>

typedef __bf16 bf16x8 __attribute__((ext_vector_type(8)));
typedef float floatx4 __attribute__((ext_vector_type(4)));

#define T_LEN 128

// ws layout: bf16 fragment-packed weights, gates KI-MAJOR:
//   gate frag addr = WP_OFF + ki*65536 + ct*1024 + lane*16
// K order: [ a(8) | z(32) | h(256) | pad(24) ]
#define WP_OFF   0
#define WP_SZ    (64*10*64*16)     // 655360
#define W1P_OFF  (WP_OFF + WP_SZ)
#define W1P_SZ   (8*8*64*16)       // 65536
#define W2P_OFF  (W1P_OFF + W1P_SZ)
#define W2P_SZ   (8*4*64*16)       // 32768
#define WZP_OFF  (W2P_OFF + W2P_SZ)
#define WZP_SZ   (4*4*64*16)       // 16384
#define WS_NEEDED ((size_t)(WZP_OFF + WZP_SZ))   // 770048 B

// ---- fast transcendentals ------------------------------------------------
#if __has_builtin(__builtin_amdgcn_exp2f)
#define EXP2F(x) __builtin_amdgcn_exp2f(x)
#else
#define EXP2F(x) exp2f(x)
#endif
#if __has_builtin(__builtin_amdgcn_logf)
#define LOG2F(x) __builtin_amdgcn_logf(x)
#else
#define LOG2F(x) log2f(x)
#endif
#if __has_builtin(__builtin_amdgcn_rcpf)
#define RCPF(x) __builtin_amdgcn_rcpf(x)
#else
#define RCPF(x) (1.0f/(x))
#endif

__device__ __forceinline__ float fsigmoid(float x) {
    return RCPF(1.0f + EXP2F(-1.4426950408889634f * x));
}
__device__ __forceinline__ float ftanh(float x) {
    return 1.0f - 2.0f * RCPF(1.0f + EXP2F(2.8853900817779268f * x));
}

// ---------------- prep: f32 weights -> bf16 B-fragment-linear in ws -------
__global__ void prep_kernel(const float* __restrict__ Wih, const float* __restrict__ Whh,
                            const float* __restrict__ W1,  const float* __restrict__ W2,
                            const float* __restrict__ Wz,  unsigned char* __restrict__ ws)
{
    int id = blockIdx.x * blockDim.x + threadIdx.x;
    __bf16* Wp  = (__bf16*)(ws + WP_OFF);
    __bf16* W1p = (__bf16*)(ws + W1P_OFF);
    __bf16* W2p = (__bf16*)(ws + W2P_OFF);
    __bf16* Wzp = (__bf16*)(ws + WZP_OFF);
    if (id < 40960) {                       // gates: 64 ct x 10 ki x 64 lanes
        int ct = id / 640, rem = id % 640;
        int ki = rem / 64, lane = rem % 64;
        int row = ct * 16 + (lane & 15);                 // gate-output col
        int kb  = ki * 32 + (lane >> 4) * 8;
        for (int j = 0; j < 8; ++j) {
            int k = kb + j;
            float v;
            if (k < 40)       v = Wih[row * 40 + k];     // [a|z] = Wih cols
            else if (k < 296) v = Whh[row * 256 + (k - 40)];
            else              v = 0.0f;                   // pad 296..319
            Wp[((size_t)(ki * 64 + ct) * 64 + lane) * 8 + j] = (__bf16)v;
        }
    } else if (id < 45056) {                // W1: 8 ct x 8 ki (ct-major)
        int id2 = id - 40960;
        int rem = id2 % 512, lane = rem % 64;
        int row = (id2 / 512) * 16 + (lane & 15);
        int kb  = (rem / 64) * 32 + (lane >> 4) * 8;
        for (int j = 0; j < 8; ++j) W1p[(size_t)id2 * 8 + j] = (__bf16)W1[row * 256 + kb + j];
    } else if (id < 47104) {                // W2: 8 ct x 4 ki
        int id3 = id - 45056;
        int rem = id3 % 256, lane = rem % 64;
        int row = (id3 / 256) * 16 + (lane & 15);
        int kb  = (rem / 64) * 32 + (lane >> 4) * 8;
        for (int j = 0; j < 8; ++j) W2p[(size_t)id3 * 8 + j] = (__bf16)W2[row * 128 + kb + j];
    } else if (id < 48128) {                // Wz: 4 ct x 4 ki
        int id4 = id - 47104;
        int rem = id4 % 256, lane = rem % 64;
        int row = (id4 / 256) * 16 + (lane & 15);
        int kb  = (rem / 64) * 32 + (lane >> 4) * 8;
        for (int j = 0; j < 8; ++j) Wzp[(size_t)id4 * 8 + j] = (__bf16)Wz[row * 128 + kb + j];
    }
}

// ---------------- fast path: 64 blocks x 512 threads (8 waves) ------------
// R7 = R5 + __launch_bounds__(512, 2).
// 2nd arg = MIN WAVES PER SIMD: with LDS (160 KB) limiting to 1 block/CU,
// 8 waves = 2 waves/SIMD exactly -> VGPR cap rises 128 -> 256, which is what
// R5's residency design needs (~230 demand). Structure unchanged from R5:
//   VGPR-resident: gate ki0,ki1 (64 regs) + W1 frags (32 regs).
//   LDS-resident:  gate ki2,ki3 (128 KB).
//   Streamed/step: gate ki4..9 (384 KB) + W2 (32 KB) + Wz (16 KB).
__global__ __launch_bounds__(512, 2) void seq_mfma(
    const float* __restrict__ A,   const float* __restrict__ eps,
    const float* __restrict__ z0,  const float* __restrict__ h0,
    const float* __restrict__ c0,
    const float* __restrict__ bih, const float* __restrict__ bhh,
    const float* __restrict__ b1,  const float* __restrict__ b2,
    const float* __restrict__ bz,
    const unsigned char* __restrict__ ws, float* __restrict__ out)
{
    const int tid  = threadIdx.x;
    const int w    = tid >> 6;          // wave 0..7
    const int lane = tid & 63;
    const int lrow = lane & 15;
    const int quad = lane >> 4;
    const int n0   = blockIdx.x * 16;

    __shared__ __align__(16) __bf16 slab23[2][32768];  // gate ki2, ki3 (128 KB)
    __shared__ __align__(16) __bf16 xh[2][16][328];    // [a(8)|z(32)|h(256)|pad]
    __shared__ __align__(16) __bf16 u1s[16][136];      // also zz f32 overlay
    __shared__ __align__(16) __bf16 u2s[16][136];
    float* zzf = (float*)&u1s[0][0];                   // [16][68] f32 view

    const char* wsb = (const char*)ws;

    // one-time: gate slabs ki2,ki3 global -> LDS (8192 x 16B)
    {
        const float4* src = (const float4*)(wsb + WP_OFF + 2 * 65536);
        float4* dst = (float4*)slab23;
        for (int i = tid; i < 8192; i += 512) dst[i] = src[i];
    }

    // init both xh buffers: a(0)=0 | z0 | h0 | pad 0
    for (int idx = tid; idx < 2 * 16 * 320; idx += 512) {
        int b = idx / (16 * 320);
        int rem = idx % (16 * 320);
        int r = rem / 320, col = rem % 320;
        float v;
        if (col >= 8 && col < 40)        v = z0[col - 8];
        else if (col >= 40 && col < 296) v = h0[col - 40];
        else                             v = 0.0f;
        xh[b][r][col] = (__bf16)v;
    }
    if (tid < 128)   // a(t=0)
        xh[0][tid >> 3][tid & 7] =
            (__bf16)A[((size_t)(n0 + (tid >> 3)) * T_LEN + 0) * 8 + (tid & 7)];

    // ---- resident weights (per-lane, compile-time indexed throughout) ----
    bf16x8 r0[4][2], r1[4][2];   // gate ki0, ki1 : ct = g*16 + 2w + j
    #pragma unroll
    for (int g = 0; g < 4; ++g)
        #pragma unroll
        for (int j = 0; j < 2; ++j) {
            const size_t cto = (size_t)(g * 16 + 2 * w + j) * 1024 + (size_t)lane * 16;
            r0[g][j] = *(const bf16x8*)(wsb + WP_OFF + cto);
            r1[g][j] = *(const bf16x8*)(wsb + WP_OFF + 65536 + cto);
        }
    bf16x8 w1f[8];               // W1 ct = w
    #pragma unroll
    for (int k = 0; k < 8; ++k)
        w1f[k] = *(const bf16x8*)(wsb + W1P_OFF + ((size_t)(w * 8 + k) * 64 + lane) * 16);

    // biases & recurrent state
    float gb[4][2];
    #pragma unroll
    for (int g = 0; g < 4; ++g)
        #pragma unroll
        for (int j = 0; j < 2; ++j) {
            int unit = 32 * w + 16 * j + lrow;
            gb[g][j] = bih[g * 256 + unit] + bhh[g * 256 + unit];
        }
    float u1b = b1[w * 16 + lrow];
    float u2b = b2[w * 16 + lrow];
    float zzb = (w < 4) ? bz[w * 16 + lrow] : 0.0f;
    float cst[2][4];
    #pragma unroll
    for (int j = 0; j < 2; ++j) {
        float cv = c0[32 * w + 16 * j + lrow];
        #pragma unroll
        for (int r = 0; r < 4; ++r) cst[j][r] = cv;
    }

    __syncthreads();

    // helper macros (all compile-time indices)
    #define GLOAD(BUF, KI) do {                                                   \
        _Pragma("unroll")                                                         \
        for (int g_ = 0; g_ < 4; ++g_)                                            \
            _Pragma("unroll")                                                     \
            for (int j_ = 0; j_ < 2; ++j_)                                        \
                BUF[g_][j_] = *(const bf16x8*)(wsb + WP_OFF + (KI) * 65536 +      \
                    ((size_t)(g_ * 16 + 2 * w + j_) * 1024 + (size_t)lane * 16)); \
    } while (0)
    #define GMFMA(KI, BUF) do {                                                   \
        bf16x8 af_ = *(const bf16x8*)&xh[cb][lrow][(KI) * 32 + quad * 8];         \
        _Pragma("unroll")                                                         \
        for (int g_ = 0; g_ < 4; ++g_)                                            \
            _Pragma("unroll")                                                     \
            for (int j_ = 0; j_ < 2; ++j_)                                        \
                acc[g_][j_] = __builtin_amdgcn_mfma_f32_16x16x32_bf16(            \
                    af_, BUF[g_][j_], acc[g_][j_], 0, 0, 0);                      \
    } while (0)
    #define GMFMA_LDS(KI) do {                                                    \
        bf16x8 af_ = *(const bf16x8*)&xh[cb][lrow][(KI) * 32 + quad * 8];         \
        _Pragma("unroll")                                                         \
        for (int g_ = 0; g_ < 4; ++g_)                                            \
            _Pragma("unroll")                                                     \
            for (int j_ = 0; j_ < 2; ++j_) {                                      \
                bf16x8 b_ = *(const bf16x8*)&slab23[(KI) - 2]                     \
                    [g_ * 8192 + w * 1024 + j_ * 512 + lane * 8];                 \
                acc[g_][j_] = __builtin_amdgcn_mfma_f32_16x16x32_bf16(            \
                    af_, b_, acc[g_][j_], 0, 0, 0);                               \
            }                                                                     \
    } while (0)

    for (int t = 0; t < T_LEN; ++t) {
        const int cb = t & 1;        // X_t
        const int nb = cb ^ 1;       // X_{t+1}

        // per-step activations (values used late; loads overlap gates)
        float eps_cur = eps[((size_t)(n0 + (tid >> 5)) * T_LEN + t) * 32 + (tid & 31)];
        float a_nxt = 0.0f;
        if (t + 1 < T_LEN && tid < 128)
            a_nxt = A[((size_t)(n0 + (tid >> 3)) * T_LEN + (t + 1)) * 8 + (tid & 7)];

        // ---- gates: resident ki0,1 + LDS ki2,3 + streamed ki4..9 ----
        bf16x8 bA[4][2], bB[4][2];
        GLOAD(bA, 4);
        GLOAD(bB, 5);

        floatx4 acc[4][2];
        #pragma unroll
        for (int g = 0; g < 4; ++g)
            #pragma unroll
            for (int j = 0; j < 2; ++j)
                acc[g][j] = (floatx4){gb[g][j], gb[g][j], gb[g][j], gb[g][j]};

        GMFMA(0, r0);
        GMFMA(1, r1);
        GMFMA_LDS(2);
        GMFMA_LDS(3);
        GMFMA(4, bA);  GLOAD(bA, 6);
        GMFMA(5, bB);  GLOAD(bB, 7);
        GMFMA(6, bA);  GLOAD(bA, 8);
        GMFMA(7, bB);  GLOAD(bB, 9);
        GMFMA(8, bA);
        GMFMA(9, bB);

        // ---- LSTM cell (own acc only) -> h_{t+1} into X_{t+1}
        #pragma unroll
        for (int j = 0; j < 2; ++j)
            #pragma unroll
            for (int r = 0; r < 4; ++r) {
                float iv = fsigmoid(acc[0][j][r]);
                float fv = fsigmoid(acc[1][j][r]);
                float gv = ftanh(acc[2][j][r]);
                float ov = fsigmoid(acc[3][j][r]);
                float cn = fv * cst[j][r] + iv * gv;
                cst[j][r] = cn;
                xh[nb][quad * 4 + r][40 + 32 * w + 16 * j + lrow] = (__bf16)(ov * ftanh(cn));
            }
        if (t + 1 < T_LEN && tid < 128)
            xh[nb][tid >> 3][tid & 7] = (__bf16)a_nxt;
        __syncthreads();   // B2: h_{t+1} + a_{t+1} staged

        // ---- u1 = relu(h @ W1^T + b1): all 8 waves, ct=w, W1 resident
        {
            floatx4 a1 = (floatx4){u1b, u1b, u1b, u1b};
            #pragma unroll
            for (int ki = 0; ki < 8; ++ki) {
                bf16x8 af = *(const bf16x8*)&xh[nb][lrow][40 + ki * 32 + quad * 8];
                a1 = __builtin_amdgcn_mfma_f32_16x16x32_bf16(af, w1f[ki], a1, 0, 0, 0);
            }
            #pragma unroll
            for (int r = 0; r < 4; ++r)
                u1s[quad * 4 + r][w * 16 + lrow] = (__bf16)fmaxf(a1[r], 0.0f);
        }
        __syncthreads();   // B3: u1s ready

        // ---- u2 = relu(u1 @ W2^T + b2): W2 streamed (issued here, used now;
        //      latency overlapped with u1s ds_reads), Wz streamed for B5 use.
        {
            bf16x8 w2f[4];
            #pragma unroll
            for (int k = 0; k < 4; ++k)
                w2f[k] = *(const bf16x8*)(wsb + W2P_OFF + ((size_t)(w * 4 + k) * 64 + lane) * 16);
            bf16x8 wzf[4];
            if (w < 4) {
                #pragma unroll
                for (int k = 0; k < 4; ++k)
                    wzf[k] = *(const bf16x8*)(wsb + WZP_OFF + ((size_t)(w * 4 + k) * 64 + lane) * 16);
            }
            floatx4 a2 = (floatx4){u2b, u2b, u2b, u2b};
            #pragma unroll
            for (int ki = 0; ki < 4; ++ki) {
                bf16x8 af = *(const bf16x8*)&u1s[lrow][ki * 32 + quad * 8];
                a2 = __builtin_amdgcn_mfma_f32_16x16x32_bf16(af, w2f[ki], a2, 0, 0, 0);
            }
            #pragma unroll
            for (int r = 0; r < 4; ++r)
                u2s[quad * 4 + r][w * 16 + lrow] = (__bf16)fmaxf(a2[r], 0.0f);
            __syncthreads();   // B4: u2s ready (u1s free for zz overlay)

            // ---- zz = u2 @ Wz^T + bz: waves 0..3 (loc ct 0,1; raw ct 2,3)
            if (w < 4) {
                floatx4 a3 = (floatx4){zzb, zzb, zzb, zzb};
                #pragma unroll
                for (int ki = 0; ki < 4; ++ki) {
                    bf16x8 af = *(const bf16x8*)&u2s[lrow][ki * 32 + quad * 8];
                    a3 = __builtin_amdgcn_mfma_f32_16x16x32_bf16(af, wzf[ki], a3, 0, 0, 0);
                }
                #pragma unroll
                for (int r = 0; r < 4; ++r)
                    zzf[(quad * 4 + r) * 68 + w * 16 + lrow] = a3[r];
            }
        }
        __syncthreads();   // B5: zz ready

        // ---- z = loc + softplus(raw)*eps -> X_{t+1}.z + out
        {
            int r = tid >> 5, c = tid & 31;
            float loc = zzf[r * 68 + c];
            float raw = zzf[r * 68 + c + 32];
            float sp  = (raw > 20.0f)
                      ? raw
                      : 0.6931471805599453f *
                        LOG2F(1.0f + EXP2F(1.4426950408889634f * raw));
            float zv  = loc + sp * eps_cur;
            xh[nb][r][8 + c] = (__bf16)zv;
            out[((size_t)(n0 + r) * T_LEN + t) * 32 + c] = zv;
        }
        __syncthreads();   // B1: X_{t+1} complete for next step
    }
    #undef GLOAD
    #undef GMFMA
    #undef GMFMA_LDS
}

// ---------------- fallback: proven R4 VALU kernel (f32 hard-coded) --------
struct SM {
    float zx[4][40]; float h[4][256]; float u1[4][128]; float u2[4][128]; float zz[4][64];
};

__global__ __launch_bounds__(256) void seq_valu(
    const float* __restrict__ A, const float* __restrict__ eps,
    const float* __restrict__ z0, const float* __restrict__ h0, const float* __restrict__ c0,
    const float* __restrict__ Wih, const float* __restrict__ Whh,
    const float* __restrict__ bih, const float* __restrict__ bhh,
    const float* __restrict__ W1, const float* __restrict__ b1,
    const float* __restrict__ W2, const float* __restrict__ b2,
    const float* __restrict__ Wz, const float* __restrict__ bz, float* __restrict__ out)
{
    __shared__ SM sm;
    const int tid = threadIdx.x;
    const int n0  = blockIdx.x * 4;
    if (tid < 128) { int rr = tid >> 5, cc = tid & 31; sm.zx[rr][8 + cc] = z0[cc]; }
    for (int i = tid; i < 4 * 256; i += 256) sm.h[i >> 8][i & 255] = h0[i & 255];
    float c[4];
    #pragma unroll
    for (int rr = 0; rr < 4; ++rr) c[rr] = c0[tid];
    float gbias[4];
    #pragma unroll
    for (int g = 0; g < 4; ++g) gbias[g] = bih[g * 256 + tid] + bhh[g * 256 + tid];

    for (int t = 0; t < T_LEN; ++t) {
        if (tid < 32) { int rr = tid >> 3, cc = tid & 7;
            sm.zx[rr][cc] = A[((size_t)(n0 + rr) * T_LEN + t) * 8 + cc]; }
        __syncthreads();
        float acc[4][4];
        #pragma unroll
        for (int g = 0; g < 4; ++g)
            #pragma unroll
            for (int rr = 0; rr < 4; ++rr) acc[g][rr] = gbias[g];
        for (int k = 0; k < 40; ++k) {
            float xv[4];
            #pragma unroll
            for (int rr = 0; rr < 4; ++rr) xv[rr] = sm.zx[rr][k];
            #pragma unroll
            for (int g = 0; g < 4; ++g) {
                float w = Wih[(size_t)(g * 256 + tid) * 40 + k];
                #pragma unroll
                for (int rr = 0; rr < 4; ++rr) acc[g][rr] += w * xv[rr];
            }
        }
        for (int k = 0; k < 256; ++k) {
            float hv[4];
            #pragma unroll
            for (int rr = 0; rr < 4; ++rr) hv[rr] = sm.h[rr][k];
            #pragma unroll
            for (int g = 0; g < 4; ++g) {
                float w = Whh[(size_t)(g * 256 + tid) * 256 + k];
                #pragma unroll
                for (int rr = 0; rr < 4; ++rr) acc[g][rr] += w * hv[rr];
            }
        }
        __syncthreads();
        #pragma unroll
        for (int rr = 0; rr < 4; ++rr) {
            float iv = 1.0f / (1.0f + expf(-acc[0][rr]));
            float fv = 1.0f / (1.0f + expf(-acc[1][rr]));
            float gv = tanhf(acc[2][rr]);
            float ov = 1.0f / (1.0f + expf(-acc[3][rr]));
            float cn = fv * c[rr] + iv * gv;
            c[rr] = cn;
            sm.h[rr][tid] = ov * tanhf(cn);
        }
        __syncthreads();
        { int col = tid & 127, rb = (tid >> 7) * 2;
          float a0 = b1[col], a1 = a0;
          for (int k = 0; k < 256; ++k) { float w = W1[(size_t)col * 256 + k];
              a0 += w * sm.h[rb][k]; a1 += w * sm.h[rb + 1][k]; }
          sm.u1[rb][col] = fmaxf(a0, 0.0f); sm.u1[rb + 1][col] = fmaxf(a1, 0.0f); }
        __syncthreads();
        { int col = tid & 127, rb = (tid >> 7) * 2;
          float a0 = b2[col], a1 = a0;
          for (int k = 0; k < 128; ++k) { float w = W2[(size_t)col * 128 + k];
              a0 += w * sm.u1[rb][k]; a1 += w * sm.u1[rb + 1][k]; }
          sm.u2[rb][col] = fmaxf(a0, 0.0f); sm.u2[rb + 1][col] = fmaxf(a1, 0.0f); }
        __syncthreads();
        { int rr = tid >> 6, col = tid & 63;
          float a0 = bz[col];
          for (int k = 0; k < 128; ++k) a0 += Wz[(size_t)col * 128 + k] * sm.u2[rr][k];
          sm.zz[rr][col] = a0; }
        __syncthreads();
        if (tid < 128) {
            int rr = tid >> 5, cc = tid & 31;
            float loc = sm.zz[rr][cc], raw = sm.zz[rr][cc + 32];
            float sp  = (raw > 20.0f) ? raw : log1pf(expf(raw));
            float ev  = eps[((size_t)(n0 + rr) * T_LEN + t) * 32 + cc];
            float zv  = loc + sp * ev;
            sm.zx[rr][8 + cc] = zv;
            out[((size_t)(n0 + rr) * T_LEN + t) * 32 + cc] = zv;
        }
        __syncthreads();
    }
}

extern "C" void kernel_launch(void* const* d_in, const int* in_sizes, int n_in,
                              void* d_out, int out_size, void* d_ws, size_t ws_size,
                              hipStream_t stream)
{
    const float* A   = (const float*)d_in[0];
    const float* eps = (const float*)d_in[1];
    const float* z0  = (const float*)d_in[2];
    const float* h0  = (const float*)d_in[3];
    const float* c0  = (const float*)d_in[4];
    const float* Wih = (const float*)d_in[5];
    const float* Whh = (const float*)d_in[6];
    const float* bih = (const float*)d_in[7];
    const float* bhh = (const float*)d_in[8];
    const float* W1  = (const float*)d_in[9];
    const float* b1  = (const float*)d_in[10];
    const float* W2  = (const float*)d_in[11];
    const float* b2  = (const float*)d_in[12];
    const float* Wz  = (const float*)d_in[13];
    const float* bz  = (const float*)d_in[14];
    float* out = (float*)d_out;

    if (ws_size >= WS_NEEDED) {
        prep_kernel<<<188, 256, 0, stream>>>(Wih, Whh, W1, W2, Wz, (unsigned char*)d_ws);
        seq_mfma<<<64, 512, 0, stream>>>(A, eps, z0, h0, c0,
                                         bih, bhh, b1, b2, bz,
                                         (const unsigned char*)d_ws, out);
    } else {
        seq_valu<<<256, 256, 0, stream>>>(A, eps, z0, h0, c0, Wih, Whh, bih, bhh,
                                          W1, b1, W2, b2, Wz, bz, out);
    }
}

// Round 8
// 1339.788 us; speedup vs baseline: 2.2673x; 1.6123x over previous
//
#include <hip/hip_runtime.h>
#include <hip/hip_bf16.h>
#include <math.h>

typedef __bf16 bf16x8 __attribute__((ext_vector_type(8)));
typedef float floatx4 __attribute__((ext_vector_type(4)));

#define T_LEN 128

// ws layout: bf16 fragment-packed weights, gates KI-MAJOR:
//   gate frag addr = WP_OFF + ki*65536 + ct*1024 + lane*16
// K order: [ a(8) | z(32) | h(256) | pad(24) ]
#define WP_OFF   0
#define WP_SZ    (64*10*64*16)     // 655360
#define W1P_OFF  (WP_OFF + WP_SZ)
#define W1P_SZ   (8*8*64*16)       // 65536
#define W2P_OFF  (W1P_OFF + W1P_SZ)
#define W2P_SZ   (8*4*64*16)       // 32768
#define WZP_OFF  (W2P_OFF + W2P_SZ)
#define WZP_SZ   (4*4*64*16)       // 16384
#define WS_NEEDED ((size_t)(WZP_OFF + WZP_SZ))   // 770048 B

// s_waitcnt imm: wait until <=N vmem outstanding (expcnt/lgkmcnt don't care)
#define WAITVM(N) (((N) & 0xF) | (0x7 << 4) | (0xF << 8) | (((N) >> 4) << 14))

// raw barrier: LDS writes visible, VMEM (DMA) loads STAY IN FLIGHT
#define BAR() do {                                                  \
    asm volatile("s_waitcnt lgkmcnt(0)" ::: "memory");              \
    __builtin_amdgcn_sched_barrier(0);                              \
    __builtin_amdgcn_s_barrier();                                   \
    __builtin_amdgcn_sched_barrier(0);                              \
} while (0)

// ---- fast transcendentals ------------------------------------------------
#if __has_builtin(__builtin_amdgcn_exp2f)
#define EXP2F(x) __builtin_amdgcn_exp2f(x)
#else
#define EXP2F(x) exp2f(x)
#endif
#if __has_builtin(__builtin_amdgcn_logf)
#define LOG2F(x) __builtin_amdgcn_logf(x)
#else
#define LOG2F(x) log2f(x)
#endif
#if __has_builtin(__builtin_amdgcn_rcpf)
#define RCPF(x) __builtin_amdgcn_rcpf(x)
#else
#define RCPF(x) (1.0f/(x))
#endif

__device__ __forceinline__ float fsigmoid(float x) {
    return RCPF(1.0f + EXP2F(-1.4426950408889634f * x));
}
__device__ __forceinline__ float ftanh(float x) {
    return 1.0f - 2.0f * RCPF(1.0f + EXP2F(2.8853900817779268f * x));
}

// async 16B/lane global->LDS DMA; LDS base wave-uniform, lands at +lane*16
__device__ __forceinline__ void dma16(const void* g, void* lds) {
    __builtin_amdgcn_global_load_lds(
        (const __attribute__((address_space(1))) void*)g,
        (__attribute__((address_space(3))) void*)lds,
        16, 0, 0);
}

// ---------------- prep: f32 weights -> bf16 B-fragment-linear in ws -------
__global__ void prep_kernel(const float* __restrict__ Wih, const float* __restrict__ Whh,
                            const float* __restrict__ W1,  const float* __restrict__ W2,
                            const float* __restrict__ Wz,  unsigned char* __restrict__ ws)
{
    int id = blockIdx.x * blockDim.x + threadIdx.x;
    __bf16* Wp  = (__bf16*)(ws + WP_OFF);
    __bf16* W1p = (__bf16*)(ws + W1P_OFF);
    __bf16* W2p = (__bf16*)(ws + W2P_OFF);
    __bf16* Wzp = (__bf16*)(ws + WZP_OFF);
    if (id < 40960) {                       // gates: 64 ct x 10 ki x 64 lanes
        int ct = id / 640, rem = id % 640;
        int ki = rem / 64, lane = rem % 64;
        int row = ct * 16 + (lane & 15);                 // gate-output col
        int kb  = ki * 32 + (lane >> 4) * 8;
        for (int j = 0; j < 8; ++j) {
            int k = kb + j;
            float v;
            if (k < 40)       v = Wih[row * 40 + k];     // [a|z] = Wih cols
            else if (k < 296) v = Whh[row * 256 + (k - 40)];
            else              v = 0.0f;                   // pad 296..319
            Wp[((size_t)(ki * 64 + ct) * 64 + lane) * 8 + j] = (__bf16)v;
        }
    } else if (id < 45056) {                // W1: 8 ct x 8 ki (ct-major)
        int id2 = id - 40960;
        int rem = id2 % 512, lane = rem % 64;
        int row = (id2 / 512) * 16 + (lane & 15);
        int kb  = (rem / 64) * 32 + (lane >> 4) * 8;
        for (int j = 0; j < 8; ++j) W1p[(size_t)id2 * 8 + j] = (__bf16)W1[row * 256 + kb + j];
    } else if (id < 47104) {                // W2: 8 ct x 4 ki
        int id3 = id - 45056;
        int rem = id3 % 256, lane = rem % 64;
        int row = (id3 / 256) * 16 + (lane & 15);
        int kb  = (rem / 64) * 32 + (lane >> 4) * 8;
        for (int j = 0; j < 8; ++j) W2p[(size_t)id3 * 8 + j] = (__bf16)W2[row * 128 + kb + j];
    } else if (id < 48128) {                // Wz: 4 ct x 4 ki
        int id4 = id - 47104;
        int rem = id4 % 256, lane = rem % 64;
        int row = (id4 / 256) * 16 + (lane & 15);
        int kb  = (rem / 64) * 32 + (lane >> 4) * 8;
        for (int j = 0; j < 8; ++j) Wzp[(size_t)id4 * 8 + j] = (__bf16)Wz[row * 128 + kb + j];
    }
}

// ---------------- fast path: 64 blocks x 512 threads (8 waves) ------------
// R8: DMA-ring weight streaming with NEVER-DRAINED vmcnt.
//  * gates stream via global_load_lds into wave-private half-slab rings
//    (slots[w][2][2048] bf16 = 4KB each; half-slab = 4 ct). Zero VGPR cost.
//  * All barriers are raw s_barrier + lgkmcnt(0): DMA stays in flight
//    across every phase. Consumption gated by STATIC-counted vmcnt(N)
//    (in-order retirement: N = #vmem ops issued after the needed slab).
//  * Next-step slabs q0(ki0,h0)/q1(ki0,h1) issued during u2/zz phases ->
//    ingress spread across the whole step, not just the gates phase.
//  * W1 VGPR-resident (32 regs); W2/Wz LDS-resident (48KB, loaded once).
//  Per-wave issue order/step: [eps, a, q2..q19 (ring refills), q0', q1', out]
//  Wait N per half-slab q: q0,q1: 7 ; q2..q18: 4 ; q19: 0.
__global__ __launch_bounds__(512) void seq_mfma(
    const float* __restrict__ A,   const float* __restrict__ eps,
    const float* __restrict__ z0,  const float* __restrict__ h0,
    const float* __restrict__ c0,
    const float* __restrict__ bih, const float* __restrict__ bhh,
    const float* __restrict__ b1,  const float* __restrict__ b2,
    const float* __restrict__ bz,
    const unsigned char* __restrict__ ws, float* __restrict__ out)
{
    const int tid  = threadIdx.x;
    const int w    = tid >> 6;          // wave 0..7
    const int lane = tid & 63;
    const int lrow = lane & 15;
    const int quad = lane >> 4;
    const int n0   = blockIdx.x * 16;

    __shared__ __align__(16) __bf16 slots[8][2][2048];   // 64 KB DMA rings
    __shared__ __align__(16) __bf16 wmlp2[(W2P_SZ + WZP_SZ) / 2];  // 48 KB
    __shared__ __align__(16) __bf16 xh[2][16][328];      // [a|z|h|pad] 21 KB
    __shared__ __align__(16) __bf16 u1s[16][136];
    __shared__ __align__(16) __bf16 u2s[16][136];
    float* zzf = (float*)&u1s[0][0];                     // [16][68] f32 overlay

    const char* wsb = (const char*)ws;

    // one-time: W2|Wz global -> LDS (3072 x 16B)
    {
        const float4* src = (const float4*)(wsb + W2P_OFF);
        float4* dst = (float4*)wmlp2;
        for (int i = tid; i < 3072; i += 512) dst[i] = src[i];
    }
    const __bf16* w2l = wmlp2;            // ct*2048 + ki*512 + lane*8
    const __bf16* wzl = wmlp2 + 16384;    // ct*2048 + ki*512 + lane*8

    // init both xh buffers: a(0)=0 | z0 | h0 | pad 0
    for (int idx = tid; idx < 2 * 16 * 320; idx += 512) {
        int b = idx / (16 * 320);
        int rem = idx % (16 * 320);
        int r = rem / 320, col = rem % 320;
        float v;
        if (col >= 8 && col < 40)        v = z0[col - 8];
        else if (col >= 40 && col < 296) v = h0[col - 40];
        else                             v = 0.0f;
        xh[b][r][col] = (__bf16)v;
    }
    if (tid < 128)   // a(t=0)
        xh[0][tid >> 3][tid & 7] =
            (__bf16)A[((size_t)(n0 + (tid >> 3)) * T_LEN + 0) * 8 + (tid & 7)];

    // W1 VGPR-resident (ct = w): 32 regs
    bf16x8 w1f[8];
    #pragma unroll
    for (int k = 0; k < 8; ++k)
        w1f[k] = *(const bf16x8*)(wsb + W1P_OFF + ((size_t)(w * 8 + k) * 64 + lane) * 16);

    // biases & recurrent state (R5's proven mapping)
    float gb[4][2];
    #pragma unroll
    for (int g = 0; g < 4; ++g)
        #pragma unroll
        for (int j = 0; j < 2; ++j) {
            int unit = 32 * w + 16 * j + lrow;
            gb[g][j] = bih[g * 256 + unit] + bhh[g * 256 + unit];
        }
    float u1b = b1[w * 16 + lrow];
    float u2b = b2[w * 16 + lrow];
    float zzb = (w < 4) ? bz[w * 16 + lrow] : 0.0f;
    float cst[2][4];
    #pragma unroll
    for (int j = 0; j < 2; ++j) {
        float cv = c0[32 * w + 16 * j + lrow];
        #pragma unroll
        for (int r = 0; r < 4; ++r) cst[j][r] = cv;
    }

    // issue ki0 half-slabs (q0,q1): ct = (2h+gg)*16 + 2w + j -> slot[h]
    #define ISSUEK0(H) do {                                                     \
        _Pragma("unroll")                                                       \
        for (int gg = 0; gg < 2; ++gg)                                          \
            _Pragma("unroll")                                                   \
            for (int j = 0; j < 2; ++j)                                         \
                dma16(wsb + WP_OFF +                                            \
                      ((size_t)((2 * (H) + gg) * 16 + 2 * w + j) * 1024) +      \
                      (size_t)lane * 16,                                        \
                      (void*)&slots[w][H][(gg * 2 + j) * 512]);                 \
    } while (0)

    ISSUEK0(0);
    ISSUEK0(1);
    __syncthreads();   // drains init loads AND q0,q1 -> slots ready for t=0

    // consume half-slab (KI,H) with wait NW; refill (KI+1,H) into same slot
    #define GHALF(KI, H, NW, DOREF) do {                                        \
        __builtin_amdgcn_s_waitcnt(WAITVM(NW));                                 \
        __builtin_amdgcn_sched_barrier(0);                                      \
        _Pragma("unroll")                                                       \
        for (int gg = 0; gg < 2; ++gg)                                          \
            _Pragma("unroll")                                                   \
            for (int j = 0; j < 2; ++j) {                                       \
                bf16x8 b_ = *(const bf16x8*)&slots[w][H][(gg * 2 + j) * 512 +   \
                                                         lane * 8];             \
                acc[2 * (H) + gg][j] = __builtin_amdgcn_mfma_f32_16x16x32_bf16( \
                    af, b_, acc[2 * (H) + gg][j], 0, 0, 0);                     \
            }                                                                   \
        __builtin_amdgcn_sched_barrier(0);                                      \
        if (DOREF) {                                                            \
            _Pragma("unroll")                                                   \
            for (int gg = 0; gg < 2; ++gg)                                      \
                _Pragma("unroll")                                               \
                for (int j = 0; j < 2; ++j)                                     \
                    dma16(wsb + WP_OFF + (size_t)((KI) + 1) * 65536 +           \
                          ((size_t)((2 * (H) + gg) * 16 + 2 * w + j) * 1024) +  \
                          (size_t)lane * 16,                                    \
                          (void*)&slots[w][H][(gg * 2 + j) * 512]);             \
        }                                                                       \
    } while (0)

    #define GKI(KI, NA, NB, DOREF) do {                                         \
        bf16x8 af = *(const bf16x8*)&xh[cb][lrow][(KI) * 32 + quad * 8];        \
        GHALF(KI, 0, NA, DOREF);                                                \
        GHALF(KI, 1, NB, DOREF);                                                \
    } while (0)

    for (int t = 0; t < T_LEN; ++t) {
        const int cb = t & 1;        // X_t
        const int nb = cb ^ 1;       // X_{t+1}

        // eps(t)/a(t+1) issued FIRST (oldest in queue; hidden under gates)
        float eps_cur = eps[((size_t)(n0 + (tid >> 5)) * T_LEN + t) * 32 + (tid & 31)];
        float a_nxt = 0.0f;
        if (t + 1 < T_LEN && tid < 128)
            a_nxt = A[((size_t)(n0 + (tid >> 3)) * T_LEN + (t + 1)) * 8 + (tid & 7)];

        // ---- gates: 10 ki x 2 half-slabs through the DMA ring
        floatx4 acc[4][2];
        #pragma unroll
        for (int g = 0; g < 4; ++g)
            #pragma unroll
            for (int j = 0; j < 2; ++j)
                acc[g][j] = (floatx4){gb[g][j], gb[g][j], gb[g][j], gb[g][j]};

        GKI(0, 7, 7, 1);
        GKI(1, 4, 4, 1);
        GKI(2, 4, 4, 1);
        GKI(3, 4, 4, 1);
        GKI(4, 4, 4, 1);
        GKI(5, 4, 4, 1);
        GKI(6, 4, 4, 1);
        GKI(7, 4, 4, 1);
        GKI(8, 4, 4, 1);
        GKI(9, 4, 0, 0);

        // ---- LSTM cell (own acc only) -> h_{t+1} into X_{t+1}
        #pragma unroll
        for (int j = 0; j < 2; ++j)
            #pragma unroll
            for (int r = 0; r < 4; ++r) {
                float iv = fsigmoid(acc[0][j][r]);
                float fv = fsigmoid(acc[1][j][r]);
                float gv = ftanh(acc[2][j][r]);
                float ov = fsigmoid(acc[3][j][r]);
                float cn = fv * cst[j][r] + iv * gv;
                cst[j][r] = cn;
                xh[nb][quad * 4 + r][40 + 32 * w + 16 * j + lrow] = (__bf16)(ov * ftanh(cn));
            }
        if (t + 1 < T_LEN && tid < 128)
            xh[nb][tid >> 3][tid & 7] = (__bf16)a_nxt;
        BAR();   // B2: h_{t+1} + a_{t+1} staged (DMA stays in flight)

        // ---- u1 = relu(h @ W1^T + b1): W1 VGPR-resident, ds-only
        {
            floatx4 a1 = (floatx4){u1b, u1b, u1b, u1b};
            #pragma unroll
            for (int ki = 0; ki < 8; ++ki) {
                bf16x8 af = *(const bf16x8*)&xh[nb][lrow][40 + ki * 32 + quad * 8];
                a1 = __builtin_amdgcn_mfma_f32_16x16x32_bf16(af, w1f[ki], a1, 0, 0, 0);
            }
            #pragma unroll
            for (int r = 0; r < 4; ++r)
                u1s[quad * 4 + r][w * 16 + lrow] = (__bf16)fmaxf(a1[r], 0.0f);
        }
        BAR();   // B3: u1s ready

        // ---- u2 = relu(u1 @ W2^T + b2): W2 LDS-resident; issue next q0
        {
            floatx4 a2 = (floatx4){u2b, u2b, u2b, u2b};
            #pragma unroll
            for (int ki = 0; ki < 4; ++ki) {
                bf16x8 af = *(const bf16x8*)&u1s[lrow][ki * 32 + quad * 8];
                bf16x8 bb = *(const bf16x8*)&w2l[w * 2048 + ki * 512 + lane * 8];
                a2 = __builtin_amdgcn_mfma_f32_16x16x32_bf16(af, bb, a2, 0, 0, 0);
            }
            #pragma unroll
            for (int r = 0; r < 4; ++r)
                u2s[quad * 4 + r][w * 16 + lrow] = (__bf16)fmaxf(a2[r], 0.0f);
        }
        ISSUEK0(0);   // next-step q0 -> slot 0 (consumed slab long done)
        BAR();   // B4: u2s ready (u1s free for zz overlay)

        // ---- zz = u2 @ Wz^T + bz: waves 0..3; issue next q1
        if (w < 4) {
            floatx4 a3 = (floatx4){zzb, zzb, zzb, zzb};
            #pragma unroll
            for (int ki = 0; ki < 4; ++ki) {
                bf16x8 af = *(const bf16x8*)&u2s[lrow][ki * 32 + quad * 8];
                bf16x8 bb = *(const bf16x8*)&wzl[w * 2048 + ki * 512 + lane * 8];
                a3 = __builtin_amdgcn_mfma_f32_16x16x32_bf16(af, bb, a3, 0, 0, 0);
            }
            #pragma unroll
            for (int r = 0; r < 4; ++r)
                zzf[(quad * 4 + r) * 68 + w * 16 + lrow] = a3[r];
        }
        ISSUEK0(1);   // next-step q1 -> slot 1
        BAR();   // B5: zz ready

        // ---- z = loc + softplus(raw)*eps -> X_{t+1}.z + out
        {
            int r = tid >> 5, c = tid & 31;
            float loc = zzf[r * 68 + c];
            float raw = zzf[r * 68 + c + 32];
            float sp  = (raw > 20.0f)
                      ? raw
                      : 0.6931471805599453f *
                        LOG2F(1.0f + EXP2F(1.4426950408889634f * raw));
            float zv  = loc + sp * eps_cur;
            xh[nb][r][8 + c] = (__bf16)zv;
            out[((size_t)(n0 + r) * T_LEN + t) * 32 + c] = zv;
        }
        BAR();   // B1: X_{t+1} complete for next step
    }
    #undef GKI
    #undef GHALF
    #undef ISSUEK0
}

// ---------------- fallback: proven R4 VALU kernel (f32 hard-coded) --------
struct SM {
    float zx[4][40]; float h[4][256]; float u1[4][128]; float u2[4][128]; float zz[4][64];
};

__global__ __launch_bounds__(256) void seq_valu(
    const float* __restrict__ A, const float* __restrict__ eps,
    const float* __restrict__ z0, const float* __restrict__ h0, const float* __restrict__ c0,
    const float* __restrict__ Wih, const float* __restrict__ Whh,
    const float* __restrict__ bih, const float* __restrict__ bhh,
    const float* __restrict__ W1, const float* __restrict__ b1,
    const float* __restrict__ W2, const float* __restrict__ b2,
    const float* __restrict__ Wz, const float* __restrict__ bz, float* __restrict__ out)
{
    __shared__ SM sm;
    const int tid = threadIdx.x;
    const int n0  = blockIdx.x * 4;
    if (tid < 128) { int rr = tid >> 5, cc = tid & 31; sm.zx[rr][8 + cc] = z0[cc]; }
    for (int i = tid; i < 4 * 256; i += 256) sm.h[i >> 8][i & 255] = h0[i & 255];
    float c[4];
    #pragma unroll
    for (int rr = 0; rr < 4; ++rr) c[rr] = c0[tid];
    float gbias[4];
    #pragma unroll
    for (int g = 0; g < 4; ++g) gbias[g] = bih[g * 256 + tid] + bhh[g * 256 + tid];

    for (int t = 0; t < T_LEN; ++t) {
        if (tid < 32) { int rr = tid >> 3, cc = tid & 7;
            sm.zx[rr][cc] = A[((size_t)(n0 + rr) * T_LEN + t) * 8 + cc]; }
        __syncthreads();
        float acc[4][4];
        #pragma unroll
        for (int g = 0; g < 4; ++g)
            #pragma unroll
            for (int rr = 0; rr < 4; ++rr) acc[g][rr] = gbias[g];
        for (int k = 0; k < 40; ++k) {
            float xv[4];
            #pragma unroll
            for (int rr = 0; rr < 4; ++rr) xv[rr] = sm.zx[rr][k];
            #pragma unroll
            for (int g = 0; g < 4; ++g) {
                float w = Wih[(size_t)(g * 256 + tid) * 40 + k];
                #pragma unroll
                for (int rr = 0; rr < 4; ++rr) acc[g][rr] += w * xv[rr];
            }
        }
        for (int k = 0; k < 256; ++k) {
            float hv[4];
            #pragma unroll
            for (int rr = 0; rr < 4; ++rr) hv[rr] = sm.h[rr][k];
            #pragma unroll
            for (int g = 0; g < 4; ++g) {
                float w = Whh[(size_t)(g * 256 + tid) * 256 + k];
                #pragma unroll
                for (int rr = 0; rr < 4; ++rr) acc[g][rr] += w * hv[rr];
            }
        }
        __syncthreads();
        #pragma unroll
        for (int rr = 0; rr < 4; ++rr) {
            float iv = 1.0f / (1.0f + expf(-acc[0][rr]));
            float fv = 1.0f / (1.0f + expf(-acc[1][rr]));
            float gv = tanhf(acc[2][rr]);
            float ov = 1.0f / (1.0f + expf(-acc[3][rr]));
            float cn = fv * c[rr] + iv * gv;
            c[rr] = cn;
            sm.h[rr][tid] = ov * tanhf(cn);
        }
        __syncthreads();
        { int col = tid & 127, rb = (tid >> 7) * 2;
          float a0 = b1[col], a1 = a0;
          for (int k = 0; k < 256; ++k) { float w = W1[(size_t)col * 256 + k];
              a0 += w * sm.h[rb][k]; a1 += w * sm.h[rb + 1][k]; }
          sm.u1[rb][col] = fmaxf(a0, 0.0f); sm.u1[rb + 1][col] = fmaxf(a1, 0.0f); }
        __syncthreads();
        { int col = tid & 127, rb = (tid >> 7) * 2;
          float a0 = b2[col], a1 = a0;
          for (int k = 0; k < 128; ++k) { float w = W2[(size_t)col * 128 + k];
              a0 += w * sm.u1[rb][k]; a1 += w * sm.u1[rb + 1][k]; }
          sm.u2[rb][col] = fmaxf(a0, 0.0f); sm.u2[rb + 1][col] = fmaxf(a1, 0.0f); }
        __syncthreads();
        { int rr = tid >> 6, col = tid & 63;
          float a0 = bz[col];
          for (int k = 0; k < 128; ++k) a0 += Wz[(size_t)col * 128 + k] * sm.u2[rr][k];
          sm.zz[rr][col] = a0; }
        __syncthreads();
        if (tid < 128) {
            int rr = tid >> 5, cc = tid & 31;
            float loc = sm.zz[rr][cc], raw = sm.zz[rr][cc + 32];
            float sp  = (raw > 20.0f) ? raw : log1pf(expf(raw));
            float ev  = eps[((size_t)(n0 + rr) * T_LEN + t) * 32 + cc];
            float zv  = loc + sp * ev;
            sm.zx[rr][8 + cc] = zv;
            out[((size_t)(n0 + rr) * T_LEN + t) * 32 + cc] = zv;
        }
        __syncthreads();
    }
}

extern "C" void kernel_launch(void* const* d_in, const int* in_sizes, int n_in,
                              void* d_out, int out_size, void* d_ws, size_t ws_size,
                              hipStream_t stream)
{
    const float* A   = (const float*)d_in[0];
    const float* eps = (const float*)d_in[1];
    const float* z0  = (const float*)d_in[2];
    const float* h0  = (const float*)d_in[3];
    const float* c0  = (const float*)d_in[4];
    const float* Wih = (const float*)d_in[5];
    const float* Whh = (const float*)d_in[6];
    const float* bih = (const float*)d_in[7];
    const float* bhh = (const float*)d_in[8];
    const float* W1  = (const float*)d_in[9];
    const float* b1  = (const float*)d_in[10];
    const float* W2  = (const float*)d_in[11];
    const float* b2  = (const float*)d_in[12];
    const float* Wz  = (const float*)d_in[13];
    const float* bz  = (const float*)d_in[14];
    float* out = (float*)d_out;

    if (ws_size >= WS_NEEDED) {
        prep_kernel<<<188, 256, 0, stream>>>(Wih, Whh, W1, W2, Wz, (unsigned char*)d_ws);
        seq_mfma<<<64, 512, 0, stream>>>(A, eps, z0, h0, c0,
                                         bih, bhh, b1, b2, bz,
                                         (const unsigned char*)d_ws, out);
    } else {
        seq_valu<<<256, 256, 0, stream>>>(A, eps, z0, h0, c0, Wih, Whh, bih, bhh,
                                          W1, b1, W2, b2, Wz, bz, out);
    }
}